// Round 8
// baseline (83.309 us; speedup 1.0000x reference)
//
#include <hip/hip_runtime.h>

// CTC batch cost, B=64 T=1024 C=512 (blank=C-1) L=128, S=2L+1=257.
// q-ratio probability-domain forward scan, packed-f32 state pairs,
// TWO independent batch recursions interleaved per wave (ILP to hide
// the serial-chain latency: dpp -> pk_fma -> pk_mul is ~15cy; one lone
// recursion leaves the SIMD idle ~70% of cycles — R7 evidence).
//   blank states: pure adds; label states: multiply by
//   q = (y_lab+eps)/(y_blank+eps);
//   loss = -(log(p255+p256) + ksum*ln2 + sum_t log eb(t)).
// Lane l owns states 4l..4l+3 as pairs X=(p0,p2), Y=(p1,p3):
//   nX = X + (s3,p1);  nY = ((X+Y) + SK*(s3,p1)) * Q
// State 256 lives only in lane 63 (pS). Neighbor exchange via DPP
// wave_shr:1 (0x138). Exact power-of-2 rescale every 16 steps.

#define EPSF 1e-7f
static constexpr int NB = 64;
static constexpr int NT = 1024;
static constexpr int NC = 512;
static constexpr int NL = 128;
static constexpr int CHUNK = 16;
static constexpr int NCH = NT / CHUNK;  // 64

typedef unsigned int uint32;
typedef float v2f __attribute__((ext_vector_type(2)));

__device__ __forceinline__ unsigned short rn_bf16(float x) {
    uint32 b = __float_as_uint(x);
    return (unsigned short)((b + 0x7FFFu + ((b >> 16) & 1u)) >> 16);
}

// ---------------- kernel A: rowsum + q-gather, grid-stride ----------------
__global__ __launch_bounds__(256) void ctc_prep(const float* __restrict__ Y,
                                                const int* __restrict__ y_true,
                                                uint32* __restrict__ qlab,
                                                float* __restrict__ eblank,
                                                int mode) {
    const int lane = threadIdx.x & 63;
    const int wslot = threadIdx.x >> 6;  // 0..3
    const int nw = gridDim.x * 4;

    for (int w = blockIdx.x * 4 + wslot; w < NB * NT; w += nw) {
        int b = w >> 10;
        const float* row = Y + (size_t)w * NC;

        float4 v0 = *reinterpret_cast<const float4*>(row + lane * 4);
        float4 v1 = *reinterpret_cast<const float4*>(row + (NC / 2) + lane * 4);
        float s = ((v0.x + v0.y) + (v0.z + v0.w)) +
                  ((v1.x + v1.y) + (v1.z + v1.w));
#pragma unroll
        for (int d = 1; d < 64; d <<= 1) s += __shfl_xor(s, d);

        if (mode == 1) {
            float rb = row[NC - 1] + EPSF;  // wave-uniform
            float inv = 1.0f / (s + NC * EPSF);
            float rbi = 1.0f / rb;
            int2 lp = *reinterpret_cast<const int2*>(y_true + b * NL + lane * 2);
            float qx = (row[lp.x] + EPSF) * rbi;
            float qy = (row[lp.y] + EPSF) * rbi;
            uint32 pk = (uint32)rn_bf16(qx) | ((uint32)rn_bf16(qy) << 16);
            qlab[(size_t)w * (NL / 2) + lane] = pk;
            if (lane == 0) eblank[w] = rb * inv;  // normalized blank prob
        } else {
            if (lane == 0) eblank[w] = 256.0f / (s + NC * EPSF);
        }
    }
}

// ---------------- DPP helpers ----------------
__device__ __forceinline__ float dpp_wave_shr1(float x) {
    // lane l <- lane l-1, lane 0 <- 0   (DPP_CTRL 0x138 = WAVE_SHR1)
    return __int_as_float(__builtin_amdgcn_update_dpp(
        0, __float_as_int(x), 0x138, 0xF, 0xF, true));
}

__device__ __forceinline__ float dpp_wave_max(float m) {
#define DPPMAX_(ctrl)                                                     \
    m = fmaxf(m, __int_as_float(__builtin_amdgcn_update_dpp(              \
                     0, __float_as_int(m), ctrl, 0xF, 0xF, true)))
    DPPMAX_(0x111); DPPMAX_(0x112); DPPMAX_(0x114); DPPMAX_(0x118);
    DPPMAX_(0x142); DPPMAX_(0x143);
#undef DPPMAX_
    return __int_as_float(
        __builtin_amdgcn_readlane(__float_as_int(m), 63));
}

__device__ __forceinline__ float dpp_wave_sum63(float v) {
#define DPPADD_(ctrl)                                                     \
    v += __int_as_float(__builtin_amdgcn_update_dpp(                      \
        0, __float_as_int(v), ctrl, 0xF, 0xF, true))
    DPPADD_(0x111); DPPADD_(0x112); DPPADD_(0x114); DPPADD_(0x118);
    DPPADD_(0x142); DPPADD_(0x143);
#undef DPPADD_
    return v;
}

// ---------------- kernel B: packed-f32 scan, 2 batches per wave ----------
__global__ __launch_bounds__(64) void ctc_rec1(const uint32* __restrict__ A,
                                               const float* __restrict__ Bv,
                                               const int* __restrict__ y_true,
                                               float* __restrict__ out) {
    const int ba = blockIdx.x * 2;
    const int bb = ba + 1;
    const int l = threadIdx.x;

    const int* labA = y_true + ba * NL;
    const int* labB = y_true + bb * NL;
    int am1 = (l == 0) ? -1 : labA[2 * l - 1];
    int a0 = labA[2 * l];
    int a1 = labA[2 * l + 1];
    int bm1 = (l == 0) ? -1 : labB[2 * l - 1];
    int b0 = labB[2 * l];
    int b1 = labB[2 * l + 1];
    v2f SKa = {(a0 != am1) ? 1.0f : 0.0f, (a1 != a0) ? 1.0f : 0.0f};
    v2f SKb = {(b0 != bm1) ? 1.0f : 0.0f, (b1 != b0) ? 1.0f : 0.0f};

    // sum_t log eb(t) per batch (interleaved logf chains)
    float slogA = 0.0f, slogB = 0.0f;
#pragma unroll
    for (int k = 0; k < NT / 64; k++) {
        slogA += logf(Bv[ba * NT + k * 64 + l]);
        slogB += logf(Bv[bb * NT + k * 64 + l]);
    }
    float sredA = dpp_wave_sum63(slogA);
    float sredB = dpp_wave_sum63(slogB);

    v2f Xa = {(l == 0) ? 1.0f : 0.0f, 0.0f}, Ya = {0.0f, 0.0f};
    v2f Xb = {(l == 0) ? 1.0f : 0.0f, 0.0f}, Yb = {0.0f, 0.0f};
    float pSa = 0.0f, pSb = 0.0f;
    int ksA = 0, ksB = 0;

    uint32 LA0[CHUNK], LB0[CHUNK], LA1[CHUNK], LB1[CHUNK];

    auto load = [&](int c, uint32(&LA)[CHUNK], uint32(&LB)[CHUNK]) {
        const uint32* pa = A + ((size_t)ba * NT + c * CHUNK) * (NL / 2) + l;
        const uint32* pb = A + ((size_t)bb * NT + c * CHUNK) * (NL / 2) + l;
#pragma unroll
        for (int j = 0; j < CHUNK; j++) {
            LA[j] = pa[(size_t)j * (NL / 2)];
            LB[j] = pb[(size_t)j * (NL / 2)];
        }
    };

    auto process = [&](uint32(&LA)[CHUNK], uint32(&LB)[CHUNK]) {
#pragma unroll
        for (int j = 0; j < CHUNK; j++) {
            float s3a = dpp_wave_shr1(Ya.y);
            float s3b = dpp_wave_shr1(Yb.y);
            v2f Qa = {__uint_as_float(LA[j] << 16),
                      __uint_as_float(LA[j] & 0xFFFF0000u)};
            v2f Qb = {__uint_as_float(LB[j] << 16),
                      __uint_as_float(LB[j] & 0xFFFF0000u)};
            v2f Sa = {s3a, Ya.x};
            v2f Sb = {s3b, Yb.x};
            v2f Ta = Xa + Ya;
            v2f Tb = Xb + Yb;
            pSa += Ya.y;
            pSb += Yb.y;
            v2f nYa = (Ta + SKa * Sa) * Qa;
            v2f nYb = (Tb + SKb * Sb) * Qb;
            Xa = Xa + Sa;
            Xb = Xb + Sb;
            Ya = nYa;
            Yb = nYb;
        }
        // exact power-of-2 rescale once per 16 steps (both batches)
        float ma = fmaxf(fmaxf(Xa.x, Ya.x), fmaxf(Xa.y, Ya.y));
        float mb = fmaxf(fmaxf(Xb.x, Yb.x), fmaxf(Xb.y, Yb.y));
        ma = fmaxf(ma, (l == 63) ? pSa : 0.0f);
        mb = fmaxf(mb, (l == 63) ? pSb : 0.0f);
        float mallA = fmaxf(dpp_wave_max(ma), 1e-30f);
        float mallB = fmaxf(dpp_wave_max(mb), 1e-30f);
        int ea = (int)(__float_as_uint(mallA) >> 23) - 127;
        int eb = (int)(__float_as_uint(mallB) >> 23) - 127;
        float sca = __uint_as_float((uint32)(127 - ea) << 23);
        float scb = __uint_as_float((uint32)(127 - eb) << 23);
        Xa = Xa * sca; Ya = Ya * sca; pSa *= sca;
        Xb = Xb * scb; Yb = Yb * scb; pSb *= scb;
        ksA += ea;
        ksB += eb;
    };

    load(0, LA0, LB0);
    for (int c = 0; c < NCH; c += 2) {
        __builtin_amdgcn_sched_barrier(0);
        if (c + 1 < NCH) load(c + 1, LA1, LB1);
        __builtin_amdgcn_sched_barrier(0);
        process(LA0, LB0);
        __builtin_amdgcn_sched_barrier(0);
        if (c + 2 < NCH) load(c + 2, LA0, LB0);
        __builtin_amdgcn_sched_barrier(0);
        process(LA1, LB1);
    }

    if (l == 63) {
        out[ba] = -(logf(Ya.y + pSa) +
                    (float)ksA * 0.69314718055994531f + sredA);
        out[bb] = -(logf(Yb.y + pSb) +
                    (float)ksB * 0.69314718055994531f + sredB);
    }
}

// ---------------- fallback scan (no staged q in ws; legacy eb-form) -------
__global__ __launch_bounds__(64) void ctc_rec0(const float* __restrict__ A,
                                               const float* __restrict__ Bv,
                                               const int* __restrict__ y_true,
                                               float* __restrict__ out) {
    const int b = blockIdx.x;
    const int l = threadIdx.x;
    const int* lab = y_true + b * NL;

    int lab_m1 = (l == 0) ? -1 : lab[2 * l - 1];
    int lab0 = lab[2 * l];
    int lab1 = lab[2 * l + 1];
    float sk0 = (lab0 != lab_m1) ? 1.0f : 0.0f;
    float sk1 = (lab1 != lab0) ? 1.0f : 0.0f;

    float p0 = (l == 0) ? 1.0f : 0.0f;
    float p1 = 0.0f, p2 = 0.0f, p3 = 0.0f, pS = 0.0f;
    int ksum = 0;

    for (int t = 0; t < NT; t++) {
        const float* base = A + ((size_t)b * NT + t) * NC;
        float iv = Bv[b * NT + t];
        float eb = (base[NC - 1] + EPSF) * iv;
        float ex = (base[lab0] + EPSF) * iv;
        float ey = (base[lab1] + EPSF) * iv;
        float s3 = dpp_wave_shr1(p3);
        float n0 = (p0 + s3) * eb;
        float n1 = (p1 + p0 + sk0 * s3) * ex;
        float n2 = (p2 + p1) * eb;
        float n3 = (p3 + p2 + sk1 * p1) * ey;
        pS = (pS + p3) * eb;
        p0 = n0; p1 = n1; p2 = n2; p3 = n3;
        if ((t & 15) == 15) {
            float m = fmaxf(fmaxf(p0, p1), fmaxf(p2, p3));
            m = fmaxf(m, (l == 63) ? pS : 0.0f);
            float mall = fmaxf(dpp_wave_max(m), 1e-30f);
            int e = (int)(__float_as_uint(mall) >> 23) - 127;
            float sc = __uint_as_float((uint32)(127 - e) << 23);
            p0 *= sc; p1 *= sc; p2 *= sc; p3 *= sc; pS *= sc;
            ksum += e;
        }
    }

    if (l == 63) {
        float tot = p3 + pS;
        out[b] = -(logf(tot) +
                   (float)(ksum - 8192) * 0.69314718055994531f);
    }
}

extern "C" void kernel_launch(void* const* d_in, const int* in_sizes, int n_in,
                              void* d_out, int out_size, void* d_ws, size_t ws_size,
                              hipStream_t stream) {
    const int* y_true = (const int*)d_in[0];
    const float* y_pred = (const float*)d_in[1];
    float* out = (float*)d_out;

    const size_t qlab_bytes = (size_t)NB * NT * (NL / 2) * sizeof(uint32);  // 16 MiB
    const size_t eb_bytes = (size_t)NB * NT * sizeof(float);                // 256 KiB

    if (ws_size >= qlab_bytes + eb_bytes) {
        uint32* qlab = (uint32*)d_ws;
        float* eblank = (float*)((char*)d_ws + qlab_bytes);
        ctc_prep<<<2048, 256, 0, stream>>>(y_pred, y_true, qlab, eblank, 1);
        ctc_rec1<<<NB / 2, 64, 0, stream>>>(qlab, eblank, y_true, out);
    } else {
        float* invb = (float*)d_ws;
        ctc_prep<<<2048, 256, 0, stream>>>(y_pred, y_true, nullptr, invb, 0);
        ctc_rec0<<<NB, 64, 0, stream>>>(y_pred, invb, y_true, out);
    }
}